// Round 4
// baseline (813.399 us; speedup 1.0000x reference)
//
#include <hip/hip_runtime.h>
#include <hip/hip_bf16.h>

// UnifiedCoreFlow: 24x { gather-cols -> GEMM(1024^3) -> clip -> quantize } -> 10-col gather.
// Strategy:
//  - Activations after quantization are exact integers k in [0,16] -> store as bf16 (exact).
//  - W split into bf16 hi+lo (combined ~2^-17 rel err) -> 2 MFMAs/frag = fp32-class accuracy
//    at bf16 MFMA rate. Layer 0 splits x as well (4 MFMAs).
//  - Per-layer kernel: 64b x 64o tiles, grid 16x16 = 256 wgs (1/CU), 512 thr (8 waves,
//    wave-tile 16b x 32o). The wg's 64 H-rows live in LDS (128KB) so the column-gather is
//    LDS-local; W is streamed fp32 from HBM exactly once (~100MB total = HBM floor).
//  - Last layer computes only the 10 needed output columns, writes d_out fp32.
// LDS tiles XOR-swizzled (16B block ^ (row>>1)&3) -> 2-way bank access on ds_read_b128 (free).
// Note: the chain is contractive (clip+quant deadzone) -> activations collapse to exact 0
// by ~layer 14; future lever: zero-tile skip. Baseline first.

#define B_DIM   1024
#define N_DIM   1024
#define BK      32
#define NSTEP   (N_DIM / BK)
#define THREADS 512

typedef __attribute__((ext_vector_type(8))) __bf16 bf16x8;
typedef __attribute__((ext_vector_type(4))) float  f32x4;

// dynamic LDS layout (bytes)
#define OFF_H      0        // 64 rows x 1024 halves = 131072 B (MID/LAST)
#define OFF_IDX    131072   // 1024 ints = 4096 B
#define OFF_A      135168   // A tile  [64][32] halves = 4096 B
#define OFF_A2     139264   // A-lo tile (FIRST only)
#define OFF_WH     143360   // W-hi tile
#define OFF_WL     147456   // W-lo tile
#define SMEM_BYTES 151552

__device__ __forceinline__ unsigned short f2bf(float f) {
  __hip_bfloat16 h = __float2bfloat16(f);
  return __builtin_bit_cast(unsigned short, h);
}
__device__ __forceinline__ float bf2f(unsigned short u) {
  __hip_bfloat16 h = __builtin_bit_cast(__hip_bfloat16, u);
  return __bfloat162float(h);
}
// swizzled half-offset within a [64][32]-half tile: 16B-block index ^ ((row>>1)&3)
__device__ __forceinline__ int swz(int r, int c) {
  return r * 32 + ((((c >> 3) ^ ((r >> 1) & 3)) << 3) | (c & 7));
}
// Tq arrives as a 1-element array; expected int32 (=16) but be robust to float bits.
__device__ __forceinline__ float tq_val(const int* p) {
  int v = *p;
  if (v >= 1 && v <= (1 << 24)) return (float)v;
  return __builtin_bit_cast(float, v);
}

// Layer 0 pre-pass: G0 = x[:, idx0] split into bf16 hi/lo, one block per row of x.
__global__ __launch_bounds__(256, 1)
void xsplit_k(const float* __restrict__ x, const int* __restrict__ gidx0,
              unsigned short* __restrict__ G0h, unsigned short* __restrict__ G0l)
{
  __shared__ float row[N_DIM];
  const int b = blockIdx.x, t = threadIdx.x;
  *(float4*)&row[t * 4] = *(const float4*)&x[(size_t)b * N_DIM + t * 4];
  __syncthreads();
  const int i0 = t * 4;
  const int4 c = *(const int4*)&gidx0[i0];
  float v0 = row[c.x], v1 = row[c.y], v2 = row[c.z], v3 = row[c.w];
  unsigned short h0 = f2bf(v0), h1 = f2bf(v1), h2 = f2bf(v2), h3 = f2bf(v3);
  unsigned short l0 = f2bf(v0 - bf2f(h0)), l1 = f2bf(v1 - bf2f(h1));
  unsigned short l2 = f2bf(v2 - bf2f(h2)), l3 = f2bf(v3 - bf2f(h3));
  *(ushort4*)&G0h[(size_t)b * N_DIM + i0] = make_ushort4(h0, h1, h2, h3);
  *(ushort4*)&G0l[(size_t)b * N_DIM + i0] = make_ushort4(l0, l1, l2, l3);
}

// MODE: 0 = FIRST (A = x hi/lo pre-gathered), 1 = MID (A = gathered k-values via LDS H rows),
//       2 = LAST (like MID, but B rows = W[out_idx[j]], writes d_out fp32)
template <int MODE>
__global__ __launch_bounds__(THREADS, 1)
void gemm_k(const unsigned short* __restrict__ Hprev,
            const unsigned short* __restrict__ G0h,
            const unsigned short* __restrict__ G0l,
            const float* __restrict__ W,
            const int* __restrict__ gidx,
            const int* __restrict__ oidx,
            const float* __restrict__ scales,
            const int* __restrict__ tqp,
            int l, int n_out,
            unsigned short* __restrict__ Hout,
            float* __restrict__ out)
{
  extern __shared__ char sm[];
  unsigned short* smH  = (unsigned short*)(sm + OFF_H);
  int*            smI  = (int*)(sm + OFF_IDX);
  unsigned short* smA  = (unsigned short*)(sm + OFF_A);
  unsigned short* smA2 = (unsigned short*)(sm + OFF_A2);
  unsigned short* smWh = (unsigned short*)(sm + OFF_WH);
  unsigned short* smWl = (unsigned short*)(sm + OFF_WL);

  const int t  = threadIdx.x;
  const int b0 = blockIdx.x * 64;
  const int o0 = blockIdx.y * 64;

  // phase 0: stage this wg's 64 H rows + this layer's gather idx into LDS
  if constexpr (MODE != 0) {
    for (int i = 0; i < 16; ++i) {
      int off = (i * THREADS + t) * 8;     // half index into 64x1024
      int r = off >> 10, c = off & 1023;
      *(int4*)&smH[r * 1024 + c] = *(const int4*)&Hprev[(size_t)(b0 + r) * N_DIM + c];
    }
    if (t < 256) *(int4*)&smI[t * 4] = *(const int4*)&gidx[t * 4];
  }

  const int sr  = t >> 3;          // staging row 0..63
  const int sc4 = (t & 7) * 4;     // staging col (4-elem granularity)

  float4  wv;                      // prefetched W row chunk (fp32)
  ushort4 av;                      // prefetched gathered A halves (MID/LAST)
  int4    a0v;                     // prefetched A halves (FIRST)

  auto prefetch = [&](int k0) {
    int orow;
    if constexpr (MODE == 2) orow = oidx[sr < n_out ? sr : 0];
    else                     orow = o0 + sr;
    wv = *(const float4*)&W[(size_t)orow * N_DIM + k0 + sc4];
    if constexpr (MODE != 0) {
      int4 iv = *(const int4*)&smI[k0 + sc4];
      av.x = smH[sr * 1024 + iv.x];
      av.y = smH[sr * 1024 + iv.y];
      av.z = smH[sr * 1024 + iv.z];
      av.w = smH[sr * 1024 + iv.w];
    } else {
      int r8 = t & 255;
      int ar = r8 >> 2, ac = (r8 & 3) * 8;
      const unsigned short* src = (t < 256) ? G0h : G0l;
      a0v = *(const int4*)&src[(size_t)(b0 + ar) * N_DIM + k0 + ac];
    }
  };

  __syncthreads();                 // H rows + idx visible
  prefetch(0);

  f32x4 acc0 = {0.f, 0.f, 0.f, 0.f};
  f32x4 acc1 = {0.f, 0.f, 0.f, 0.f};

  const int lane = t & 63;
  const int w    = t >> 6;
  const int g    = lane >> 4;
  const int ln   = lane & 15;
  const int wm   = w >> 1;         // 0..3 : b-offset 16*wm
  const int wn   = w & 1;          // 0..1 : o-offset 32*wn
  const int aoff  = swz(wm * 16 + ln,      g * 8);
  const int boff0 = swz(wn * 32 + ln,      g * 8);
  const int boff1 = swz(wn * 32 + 16 + ln, g * 8);

  for (int s = 0; s < NSTEP; ++s) {
    __syncthreads();               // previous step's compute done; tiles writable
    {
      float f0 = wv.x, f1 = wv.y, f2 = wv.z, f3 = wv.w;
      unsigned short h0 = f2bf(f0), h1 = f2bf(f1), h2 = f2bf(f2), h3 = f2bf(f3);
      unsigned short w0 = f2bf(f0 - bf2f(h0)), w1 = f2bf(f1 - bf2f(h1));
      unsigned short w2 = f2bf(f2 - bf2f(h2)), w3 = f2bf(f3 - bf2f(h3));
      int ofs = swz(sr, sc4);
      *(ushort4*)&smWh[ofs] = make_ushort4(h0, h1, h2, h3);
      *(ushort4*)&smWl[ofs] = make_ushort4(w0, w1, w2, w3);
      if constexpr (MODE != 0) {
        *(ushort4*)&smA[ofs] = av;
      } else {
        int r8 = t & 255;
        int ar = r8 >> 2, ac = (r8 & 3) * 8;
        unsigned short* dst = (t < 256) ? smA : smA2;
        *(int4*)&dst[swz(ar, ac)] = a0v;
      }
    }
    __syncthreads();
    if (s + 1 < NSTEP) prefetch((s + 1) * BK);   // overlaps with compute below

    bf16x8 afr = *(const bf16x8*)&smA[aoff];
    bf16x8 bh0 = *(const bf16x8*)&smWh[boff0];
    bf16x8 bl0 = *(const bf16x8*)&smWl[boff0];
    bf16x8 bh1 = *(const bf16x8*)&smWh[boff1];
    bf16x8 bl1 = *(const bf16x8*)&smWl[boff1];
    acc0 = __builtin_amdgcn_mfma_f32_16x16x32_bf16(afr, bh0, acc0, 0, 0, 0);
    acc0 = __builtin_amdgcn_mfma_f32_16x16x32_bf16(afr, bl0, acc0, 0, 0, 0);
    acc1 = __builtin_amdgcn_mfma_f32_16x16x32_bf16(afr, bh1, acc1, 0, 0, 0);
    acc1 = __builtin_amdgcn_mfma_f32_16x16x32_bf16(afr, bl1, acc1, 0, 0, 0);
    if constexpr (MODE == 0) {
      bf16x8 afr2 = *(const bf16x8*)&smA2[aoff];
      acc0 = __builtin_amdgcn_mfma_f32_16x16x32_bf16(afr2, bh0, acc0, 0, 0, 0);
      acc0 = __builtin_amdgcn_mfma_f32_16x16x32_bf16(afr2, bl0, acc0, 0, 0, 0);
      acc1 = __builtin_amdgcn_mfma_f32_16x16x32_bf16(afr2, bh1, acc1, 0, 0, 0);
      acc1 = __builtin_amdgcn_mfma_f32_16x16x32_bf16(afr2, bl1, acc1, 0, 0, 0);
    }
  }

  // epilogue: y = acc * (s_{l-1}/Tq)   (l=0: *1) ; clip [0, s_l]; k = rint(y * Tq/s_l)
  const float Tqf = tq_val(tqp);
  const float sl  = scales[l];
  const float pf  = (l == 0) ? 1.0f : scales[l - 1] / Tqf;
  const float rq  = Tqf / sl;
  const float fq  = sl / Tqf;

  f32x4 accs[2] = {acc0, acc1};
  #pragma unroll
  for (int fn = 0; fn < 2; ++fn) {
    const int ocl = wn * 32 + fn * 16 + ln;   // o within tile (C/D col = lane&15)
    #pragma unroll
    for (int r = 0; r < 4; ++r) {
      const int br = b0 + wm * 16 + g * 4 + r;  // C/D row = 4*(lane>>4)+reg
      float y = accs[fn][r] * pf;
      y = fminf(fmaxf(y, 0.0f), sl);
      float kq = rintf(y * rq);
      if constexpr (MODE == 2) {
        if (ocl < n_out) out[(size_t)br * n_out + ocl] = kq * fq;
      } else {
        Hout[(size_t)br * N_DIM + (o0 + ocl)] = f2bf(kq);   // k exact in bf16
      }
    }
  }
}

extern "C" void kernel_launch(void* const* d_in, const int* in_sizes, int n_in,
                              void* d_out, int out_size, void* d_ws, size_t ws_size,
                              hipStream_t stream) {
  const float* x      = (const float*)d_in[0];
  const float* W      = (const float*)d_in[1];
  const int*   gidx   = (const int*)d_in[2];
  const float* scales = (const float*)d_in[3];
  const int*   oidx   = (const int*)d_in[4];
  const int*   tqp    = (const int*)d_in[5];
  float*       out    = (float*)d_out;
  const int L     = in_sizes[3];
  const int n_out = in_sizes[4];

  unsigned short* G0h = (unsigned short*)d_ws;
  unsigned short* G0l = G0h + (size_t)B_DIM * N_DIM;
  unsigned short* Ha  = G0l + (size_t)B_DIM * N_DIM;
  unsigned short* Hb  = Ha  + (size_t)B_DIM * N_DIM;

  hipFuncSetAttribute((const void*)&gemm_k<0>, hipFuncAttributeMaxDynamicSharedMemorySize, SMEM_BYTES);
  hipFuncSetAttribute((const void*)&gemm_k<1>, hipFuncAttributeMaxDynamicSharedMemorySize, SMEM_BYTES);
  hipFuncSetAttribute((const void*)&gemm_k<2>, hipFuncAttributeMaxDynamicSharedMemorySize, SMEM_BYTES);

  xsplit_k<<<dim3(B_DIM), 256, 0, stream>>>(x, gidx, G0h, G0l);

  dim3 grid(16, 16);
  gemm_k<0><<<grid, THREADS, SMEM_BYTES, stream>>>(
      nullptr, G0h, G0l, W, nullptr, nullptr, scales, tqp, 0, n_out, Ha, nullptr);

  unsigned short* hp = Ha;
  unsigned short* hn = Hb;
  for (int l = 1; l < L - 1; ++l) {
    gemm_k<1><<<grid, THREADS, SMEM_BYTES, stream>>>(
        hp, nullptr, nullptr, W + (size_t)l * N_DIM * N_DIM, gidx + (size_t)l * N_DIM,
        nullptr, scales, tqp, l, n_out, hn, nullptr);
    unsigned short* tmp = hp; hp = hn; hn = tmp;
  }
  gemm_k<2><<<dim3(16, 1), THREADS, SMEM_BYTES, stream>>>(
      hp, nullptr, nullptr, W + (size_t)(L - 1) * N_DIM * N_DIM, gidx + (size_t)(L - 1) * N_DIM,
      oidx, scales, tqp, L - 1, n_out, nullptr, out);
}